// Round 5
// baseline (1563.044 us; speedup 1.0000x reference)
//
#include <hip/hip_runtime.h>
#include <hip/hip_bf16.h>

// ---------------------------------------------------------------------------
// myLSTM: LSTM(B=64,T=512,D=256,H=256) + single-head attn (only t=0 query is
// consumed by the head!) + MLP head.
// Pipeline:
//   prep_x      : x fp32 -> bf16 (same layout)
//   prep_wit    : Wi fp32 [256,1024] -> bf16 transposed [1024,256]
//   init_hx     : set all h-exchange tag dwords to 0xFFFFFFFF
//   xg_gemm     : xg = x@Wi + b (bf16 MFMA). Epilogue writes GATE-PACKED
//                 layout xg[(b*512+t)*1024 + unit*4 + gate] so the scan loads
//                 one 8B word per (batch,unit) = all 4 gates.
//   lstm_scan   : persistent *16*-WG kernel (4 batch-groups x 4 unit-groups
//                 of 64 units). Wh slice lives in VGPRs (32 B-frags = 128
//                 VGPR/lane, loaded once) -> zero per-step LDS for B, LDS
//                 only holds hA (h_{t-1}). Each wave owns 16 units x 4 gates
//                 => gates + cell state fully register-resident. h exchanged
//                 via 8B TAGGED words {2 units | tag=t}, relaxed agent-scope
//                 atomics (single-copy-atomic => one fabric leg, no fences).
//                 4 producers/group, 6x8B polls/thread: ~5x less MALL traffic
//                 than the 64-WG round-4 version.
//   attn_qu     : q0 = h0@Wq+bq ; u = Wk@(scale*q0) ; cb = scale*q0.bk
//   attn_sm     : scores = u.h[b,t]+cb -> softmax -> hbar = sum attn*h
//   head        : o0=hbar@Wv+bv ; o1=o0@Wo+bo ; z=relu(o1@W1+b1) ; out=z@W2+b2
// ---------------------------------------------------------------------------

typedef __attribute__((ext_vector_type(8))) short short8;   // 8 x bf16 (4 VGPR)
typedef __attribute__((ext_vector_type(4))) float float4v;  // MFMA acc

__device__ __forceinline__ unsigned short f2bf(float f) {  // RNE f32->bf16
  unsigned u = __builtin_bit_cast(unsigned, f);
  return (unsigned short)((u + 0x7fffu + ((u >> 16) & 1u)) >> 16);
}
__device__ __forceinline__ float bf2f(unsigned short h) {
  return __builtin_bit_cast(float, ((unsigned)h) << 16);
}
__device__ __forceinline__ float bcl(unsigned u) {  // low bf16 of dword
  return __builtin_bit_cast(float, u << 16);
}
__device__ __forceinline__ float bch(unsigned u) {  // high bf16 of dword
  return __builtin_bit_cast(float, u & 0xffff0000u);
}
__device__ __forceinline__ float sigm(float x) { return 1.f / (1.f + __expf(-x)); }
__device__ __forceinline__ float tanh_f(float x) { return 1.f - 2.f / (1.f + __expf(2.f * x)); }

// ---------------------------------------------------------------- prep kernels
__global__ void prep_x(const float* __restrict__ x, unsigned short* __restrict__ xbf) {
  size_t i = ((size_t)blockIdx.x * 256 + threadIdx.x) * 4;  // 8,388,608 elems
  float4 v = *(const float4*)&x[i];
  unsigned long long pk = (unsigned long long)f2bf(v.x)
                        | ((unsigned long long)f2bf(v.y) << 16)
                        | ((unsigned long long)f2bf(v.z) << 32)
                        | ((unsigned long long)f2bf(v.w) << 48);
  *(unsigned long long*)&xbf[i] = pk;
}

__global__ void prep_wit(const float* __restrict__ Wi, unsigned short* __restrict__ WiT) {
  size_t i = ((size_t)blockIdx.x * 256 + threadIdx.x) * 4;  // 262,144 elems
  float4 v = *(const float4*)&Wi[i];
  int k = (int)(i >> 10), n = (int)(i & 1023);
  WiT[(size_t)(n + 0) * 256 + k] = f2bf(v.x);
  WiT[(size_t)(n + 1) * 256 + k] = f2bf(v.y);
  WiT[(size_t)(n + 2) * 256 + k] = f2bf(v.z);
  WiT[(size_t)(n + 3) * 256 + k] = f2bf(v.w);
}

__global__ void init_hx(unsigned long long* __restrict__ hx) {
  // tag dword := 0xFFFFFFFF (never equals any t in [0,512))
  hx[(size_t)blockIdx.x * 256 + threadIdx.x] = 0xffffffff00000000ULL;
}

// ---------------------------------------------------------------- xg = x@Wi+b
#define XKP 40  // LDS k-pitch (shorts): 80B rows -> 16B-aligned b128, ~2-way banks
__global__ __launch_bounds__(256) void xg_gemm(const unsigned short* __restrict__ xbf,
                                               const unsigned short* __restrict__ WiT,
                                               const float* __restrict__ bias,
                                               unsigned short* __restrict__ xg) {
  __shared__ unsigned short As[128 * XKP];
  __shared__ unsigned short Bs[128 * XKP];
  const int tid = threadIdx.x;
  const int n0 = blockIdx.x * 128, m0 = blockIdx.y * 128;
  const int wave = tid >> 6, lane = tid & 63, quad = lane >> 4, l16 = lane & 15;
  const int wm = wave >> 1, wn = wave & 1;

  float4v acc[4][4];
#pragma unroll
  for (int i = 0; i < 4; ++i)
#pragma unroll
    for (int j = 0; j < 4; ++j) acc[i][j] = (float4v){0.f, 0.f, 0.f, 0.f};

  const int rr = tid >> 2, c8 = (tid & 3) * 8;  // staging coords (16B per thread)
  for (int k0 = 0; k0 < 256; k0 += 32) {
#pragma unroll
    for (int pp = 0; pp < 2; ++pp) {
      int r = pp * 64 + rr;
      *(uint4*)&As[r * XKP + c8] = *(const uint4*)&xbf[(size_t)(m0 + r) * 256 + k0 + c8];
      *(uint4*)&Bs[r * XKP + c8] = *(const uint4*)&WiT[(size_t)(n0 + r) * 256 + k0 + c8];
    }
    __syncthreads();
#pragma unroll
    for (int mt = 0; mt < 4; ++mt) {
      short8 af = *(const short8*)&As[(wm * 64 + mt * 16 + l16) * XKP + quad * 8];
#pragma unroll
      for (int nt = 0; nt < 4; ++nt) {
        short8 bf = *(const short8*)&Bs[(wn * 64 + nt * 16 + l16) * XKP + quad * 8];
        acc[mt][nt] = __builtin_amdgcn_mfma_f32_16x16x32_bf16(af, bf, acc[mt][nt], 0, 0, 0);
      }
    }
    __syncthreads();
  }
  // epilogue: +bias, bf16 store, GATE-PACKED layout for the scan:
  //   xg[(b*512+t)*1024 + unit*4 + gate]   (unit=col&255, gate=col>>8)
  // C layout: col=lane&15, row=quad*4+reg.
#pragma unroll
  for (int nt = 0; nt < 4; ++nt) {
    int col = n0 + wn * 64 + nt * 16 + l16;
    int gate = col >> 8, gu = col & 255;
    float bv = bias[col];
#pragma unroll
    for (int mt = 0; mt < 4; ++mt) {
#pragma unroll
      for (int r = 0; r < 4; ++r) {
        int m = m0 + wm * 64 + mt * 16 + quad * 4 + r;  // m = b*512 + t
        xg[(size_t)m * 1024 + gu * 4 + gate] = f2bf(acc[mt][nt][r] + bv);
      }
    }
  }
}

// ---------------------------------------------------------------- LSTM scan
// 16 WGs: bg = blk>>2 (4 groups of 16 batches), ug = blk&3 (4 groups of 64
// units). Wave w owns units ug*64 + w*16 .. +16, ALL 4 gates (4 col-tiles).
// B (Wh slice) in VGPRs: Bfrag[gate][kt], 32 frags = 128 VGPR/lane.
// hx word layout (ull): [parity][batch(64)][word(128)]: word w = units
// 2w,2w+1 as {lo: u0|u1<<16, hi: tag=t}.
#define KP2 264  // 528B rows: 16B aligned, 2-way banks on frag reads
__global__ __launch_bounds__(256, 1) void lstm_scan(const float* __restrict__ Wh,
                                                    const unsigned short* __restrict__ xgbuf,
                                                    unsigned short* __restrict__ hout,
                                                    unsigned long long* __restrict__ hx) {
  __shared__ unsigned short stage[64 * KP2];  // 33.8 KB (B-frag staging, init only)
  __shared__ unsigned short hA[16 * KP2];     // 8.4 KB  [batch][k] h_{t-1} bf16
  const int tid = threadIdx.x;
  const int blk = blockIdx.x, bg = blk >> 2, ug = blk & 3;
  const int wave = tid >> 6, lane = tid & 63, quad = lane >> 4, l16 = lane & 15;
  const int gu = ug * 64 + wave * 16 + l16;  // this thread's global unit

  // ---- load Wh slice into registers: Bfrag[gate][kt] (gate-major staging)
  short8 Bfrag[4][8];
#pragma unroll
  for (int g = 0; g < 4; ++g) {
    for (int idx = tid; idx < 64 * 256; idx += 256) {
      int u = idx & 63, k = idx >> 6;
      stage[u * KP2 + k] = f2bf(Wh[(size_t)k * 1024 + g * 256 + ug * 64 + u]);
    }
    __syncthreads();
#pragma unroll
    for (int kt = 0; kt < 8; ++kt)
      Bfrag[g][kt] = *(const short8*)&stage[(wave * 16 + l16) * KP2 + kt * 32 + quad * 8];
    __syncthreads();
  }
  for (int i = tid; i < 16 * KP2; i += 256) hA[i] = 0;  // h_{-1} = 0
  __syncthreads();

  // cell state: 4 batches (quad*4+r) x 1 unit (gu) per thread, in registers
  float creg[4] = {0.f, 0.f, 0.f, 0.f};

  // xg pointers: one 8B word per (batch,t) = 4 gates of unit gu
  const unsigned short* xgb[4];
#pragma unroll
  for (int r = 0; r < 4; ++r)
    xgb[r] = xgbuf + ((size_t)(bg * 16 + quad * 4 + r) * 512) * 1024 + gu * 4;

  // poll word indices (constant per thread): 6 foreign words of batch b2
  const int b2 = tid >> 4, pidx = tid & 15;
  const int batchg = bg * 16 + b2;
  int gw[6];
#pragma unroll
  for (int j = 0; j < 6; ++j) {
    int f = pidx * 6 + j;                       // 0..95 foreign word index
    gw[j] = f + ((f >= ug * 32) ? 32 : 0);      // skip own 32-word block
  }

  // preload xg(0)
  ushort4 xv[4];
#pragma unroll
  for (int r = 0; r < 4; ++r) xv[r] = *(const ushort4*)xgb[r];

  for (int t = 0; t < 512; ++t) {
    // ---- MFMA: acc[g] = h_{t-1} @ Wh[:,gate g cols of own 16 units]
    float4v acc[4];
#pragma unroll
    for (int g = 0; g < 4; ++g) acc[g] = (float4v){0.f, 0.f, 0.f, 0.f};
#pragma unroll
    for (int kt = 0; kt < 8; ++kt) {
      short8 af = *(const short8*)&hA[l16 * KP2 + kt * 32 + quad * 8];
#pragma unroll
      for (int g = 0; g < 4; ++g)
        acc[g] = __builtin_amdgcn_mfma_f32_16x16x32_bf16(af, Bfrag[g][kt], acc[g], 0, 0, 0);
    }

    // ---- prefetch xg(t+1)
    int tn = (t < 511) ? t + 1 : t;
    ushort4 nxv[4];
#pragma unroll
    for (int r = 0; r < 4; ++r) nxv[r] = *(const ushort4*)(xgb[r] + (size_t)tn * 1024);

    // ---- gates fully in registers: thread owns (batch quad*4+r, unit gu)
    unsigned hb[4];
#pragma unroll
    for (int r = 0; r < 4; ++r) {
      float gi = acc[0][r] + bf2f(xv[r].x);
      float gf = acc[1][r] + bf2f(xv[r].y);
      float gG = acc[2][r] + bf2f(xv[r].z);
      float go = acc[3][r] + bf2f(xv[r].w);
      float c = sigm(gf) * creg[r] + sigm(gi) * tanh_f(gG);
      creg[r] = c;
      hb[r] = (unsigned)f2bf(sigm(go) * tanh_f(c));
    }
    __syncthreads();  // all waves done READING hA for step t

    // ---- own h into hA + hout history + tagged hx words
    const unsigned tg = (unsigned)t;
#pragma unroll
    for (int r = 0; r < 4; ++r) {
      int b = bg * 16 + quad * 4 + r;
      hA[(quad * 4 + r) * KP2 + gu] = (unsigned short)hb[r];
      hout[((size_t)b * 512 + t) * 256 + gu] = (unsigned short)hb[r];
      unsigned nb = (unsigned)__shfl_down((int)hb[r], 1);
      if ((l16 & 1) == 0) {
        unsigned long long val =
            (unsigned long long)(hb[r] | (nb << 16)) | ((unsigned long long)tg << 32);
        __hip_atomic_store(&hx[((size_t)(t & 1) * 64 + b) * 128 + (gu >> 1)], val,
                           __ATOMIC_RELAXED, __HIP_MEMORY_SCOPE_AGENT);
      }
    }

    // ---- poll 6 foreign tagged words for batch batchg
    {
      const unsigned long long* base = hx + ((size_t)(t & 1) * 64 + batchg) * 128;
      unsigned long long w[6];
      int guard = 0;
      bool ok;
      do {
        ok = true;
#pragma unroll
        for (int j = 0; j < 6; ++j) {
          w[j] = __hip_atomic_load(&base[gw[j]], __ATOMIC_RELAXED,
                                   __HIP_MEMORY_SCOPE_AGENT);
          ok &= ((unsigned)(w[j] >> 32) == tg);
        }
      } while (!ok && ++guard < (1 << 20));
#pragma unroll
      for (int j = 0; j < 6; ++j)
        *(unsigned*)&hA[b2 * KP2 + gw[j] * 2] = (unsigned)w[j];
    }
    xv[0] = nxv[0]; xv[1] = nxv[1]; xv[2] = nxv[2]; xv[3] = nxv[3];
    __syncthreads();  // hA(t) complete before next step's MFMA
  }
}

// ---------------------------------------------------------------- attention
__global__ __launch_bounds__(256) void attn_qu(const unsigned short* __restrict__ hout,
                                               const float* __restrict__ Wq,
                                               const float* __restrict__ bq,
                                               const float* __restrict__ Wk,
                                               const float* __restrict__ bk,
                                               float* __restrict__ us,
                                               float* __restrict__ cbuf) {
  __shared__ float h0S[256], q0S[256], red[256];
  const int b = blockIdx.x, tid = threadIdx.x;
  h0S[tid] = bf2f(hout[(size_t)b * 512 * 256 + tid]);
  __syncthreads();
  float a = 0.f;
  for (int k = 0; k < 256; ++k) a += h0S[k] * Wq[(size_t)k * 256 + tid];
  q0S[tid] = a + bq[tid];
  __syncthreads();
  red[tid] = q0S[tid] * bk[tid];
  __syncthreads();
  for (int s = 128; s > 0; s >>= 1) {
    if (tid < s) red[tid] += red[tid + s];
    __syncthreads();
  }
  if (tid == 0) cbuf[b] = 0.0625f * red[0];
  // u[d] = scale * dot(Wk row d, q0)
  float acc = 0.f;
  const float* wr = &Wk[(size_t)tid * 256];
  for (int e = 0; e < 256; e += 4) {
    float4 w = *(const float4*)&wr[e];
    acc += w.x * q0S[e] + w.y * q0S[e + 1] + w.z * q0S[e + 2] + w.w * q0S[e + 3];
  }
  us[b * 256 + tid] = 0.0625f * acc;
}

__global__ __launch_bounds__(256) void attn_sm(const unsigned short* __restrict__ hout,
                                               const float* __restrict__ us,
                                               const float* __restrict__ cbuf,
                                               float* __restrict__ hbar) {
  __shared__ float sS[512], red[256], hb4[4][256];
  const int b = blockIdx.x, tid = threadIdx.x, wave = tid >> 6, lane = tid & 63;
  const size_t hb_base = (size_t)b * 512 * 256;
  const float u0 = us[b * 256 + lane * 4 + 0], u1 = us[b * 256 + lane * 4 + 1];
  const float u2 = us[b * 256 + lane * 4 + 2], u3 = us[b * 256 + lane * 4 + 3];
  const float cbv = cbuf[b];
  for (int i = 0; i < 128; ++i) {
    int t = i * 4 + wave;
    unsigned long long hv = *(const unsigned long long*)&hout[hb_base + (size_t)t * 256 + lane * 4];
    unsigned lo = (unsigned)hv, hi = (unsigned)(hv >> 32);
    float p = u0 * bcl(lo) + u1 * bch(lo) + u2 * bcl(hi) + u3 * bch(hi);
    for (int m = 1; m < 64; m <<= 1) p += __shfl_xor(p, m, 64);
    if (lane == 0) sS[t] = p + cbv;
  }
  __syncthreads();
  red[tid] = fmaxf(sS[tid], sS[tid + 256]);
  __syncthreads();
  for (int s = 128; s > 0; s >>= 1) {
    if (tid < s) red[tid] = fmaxf(red[tid], red[tid + s]);
    __syncthreads();
  }
  float mx = red[0];
  __syncthreads();
  float e0 = __expf(sS[tid] - mx), e1 = __expf(sS[tid + 256] - mx);
  sS[tid] = e0; sS[tid + 256] = e1;
  red[tid] = e0 + e1;
  __syncthreads();
  for (int s = 128; s > 0; s >>= 1) {
    if (tid < s) red[tid] += red[tid + s];
    __syncthreads();
  }
  float inv = 1.f / red[0];
  // hbar[d] = (sum_t e[t]*h[t,d]) * inv  — per-wave partials over t
  float a0 = 0.f, a1 = 0.f, a2 = 0.f, a3 = 0.f;
  const int d0 = lane * 4;
  for (int i = 0; i < 128; ++i) {
    int t = wave * 128 + i;
    float w = sS[t];
    unsigned long long hv = *(const unsigned long long*)&hout[hb_base + (size_t)t * 256 + d0];
    unsigned lo = (unsigned)hv, hi = (unsigned)(hv >> 32);
    a0 += w * bcl(lo); a1 += w * bch(lo); a2 += w * bcl(hi); a3 += w * bch(hi);
  }
  hb4[wave][d0] = a0; hb4[wave][d0 + 1] = a1; hb4[wave][d0 + 2] = a2; hb4[wave][d0 + 3] = a3;
  __syncthreads();
  hbar[b * 256 + tid] = (hb4[0][tid] + hb4[1][tid] + hb4[2][tid] + hb4[3][tid]) * inv;
}

// ---------------------------------------------------------------- MLP head
__global__ __launch_bounds__(256) void head_k(const float* __restrict__ hbar,
                                              const float* __restrict__ Wv, const float* __restrict__ bv,
                                              const float* __restrict__ Wo, const float* __restrict__ bo,
                                              const float* __restrict__ W1, const float* __restrict__ b1,
                                              const float* __restrict__ W2, const float* __restrict__ b2,
                                              float* __restrict__ out) {
  __shared__ float hS[256], oS[256], o1S[256], zS[32];
  const int b = blockIdx.x, tid = threadIdx.x;
  hS[tid] = hbar[b * 256 + tid];
  __syncthreads();
  float a = 0.f;
  for (int k = 0; k < 256; ++k) a += hS[k] * Wv[(size_t)k * 256 + tid];
  oS[tid] = a + bv[tid];
  __syncthreads();
  a = 0.f;
  for (int k = 0; k < 256; ++k) a += oS[k] * Wo[(size_t)k * 256 + tid];
  o1S[tid] = a + bo[tid];
  __syncthreads();
  if (tid < 32) {
    a = 0.f;
    for (int k = 0; k < 256; ++k) a += o1S[k] * W1[k * 32 + tid];
    zS[tid] = fmaxf(a + b1[tid], 0.f);
  }
  __syncthreads();
  if (tid < 3) {
    a = 0.f;
    for (int j = 0; j < 32; ++j) a += zS[j] * W2[j * 3 + tid];
    out[b * 3 + tid] = a + b2[tid];
  }
}

// ---------------------------------------------------------------- launch
extern "C" void kernel_launch(void* const* d_in, const int* in_sizes, int n_in,
                              void* d_out, int out_size, void* d_ws, size_t ws_size,
                              hipStream_t stream) {
  const float* x  = (const float*)d_in[0];
  const float* Wi = (const float*)d_in[1];
  const float* Wh = (const float*)d_in[2];
  const float* bG = (const float*)d_in[3];
  const float* Wq = (const float*)d_in[4];
  const float* bq = (const float*)d_in[5];
  const float* Wk = (const float*)d_in[6];
  const float* bk = (const float*)d_in[7];
  const float* Wv = (const float*)d_in[8];
  const float* bv = (const float*)d_in[9];
  const float* Wo = (const float*)d_in[10];
  const float* bo = (const float*)d_in[11];
  const float* W1 = (const float*)d_in[12];
  const float* b1 = (const float*)d_in[13];
  const float* W2 = (const float*)d_in[14];
  const float* b2 = (const float*)d_in[15];
  float* out = (float*)d_out;
  char* ws = (char*)d_ws;

  unsigned short* xg    = (unsigned short*)(ws);              // 67,108,864 B
  unsigned short* hout  = (unsigned short*)(ws + 67108864);   // 16,777,216 B
  unsigned short* xbf   = (unsigned short*)(ws + 83886080);   // 16,777,216 B
  unsigned short* WiT   = (unsigned short*)(ws + 100663296);  //    524,288 B
  unsigned long long* hx = (unsigned long long*)(ws + 101187584);  // 131,072 B
  float*          us    = (float*)(ws + 101318656);           //     65,536 B
  float*          cbuf  = (float*)(ws + 101384192);           //      1,024 B
  float*          hbar  = (float*)(ws + 101385216);           //     65,536 B
  // total ~101.5 MB of workspace

  prep_x<<<dim3(8192), dim3(256), 0, stream>>>(x, xbf);
  prep_wit<<<dim3(256), dim3(256), 0, stream>>>(Wi, WiT);
  init_hx<<<dim3(64), dim3(256), 0, stream>>>(hx);
  xg_gemm<<<dim3(8, 256), dim3(256), 0, stream>>>(xbf, WiT, bG, xg);
  lstm_scan<<<dim3(16), dim3(256), 0, stream>>>(Wh, xg, hout, hx);
  attn_qu<<<dim3(64), dim3(256), 0, stream>>>(hout, Wq, bq, Wk, bk, us, cbuf);
  attn_sm<<<dim3(64), dim3(256), 0, stream>>>(hout, us, cbuf, hbar);
  head_k<<<dim3(64), dim3(256), 0, stream>>>(hbar, Wv, bv, Wo, bo, W1, b1, W2, b2, out);
}